// Round 15
// baseline (331.161 us; speedup 1.0000x reference)
//
#include <hip/hip_runtime.h>

#define LL  128
#define STR 131            // odd; rows contiguous; column strides spread mod 32
#define NT  1024

__device__ __forceinline__ float softplus_f(float x) { return log1pf(__expf(x)); }

// LDS-visibility-only barrier (no vmcnt drain).
__device__ __forceinline__ void lds_barrier() {
    asm volatile("s_waitcnt lgkmcnt(0)" ::: "memory");
    __builtin_amdgcn_s_barrier();
    asm volatile("" ::: "memory");
}

// LDS:
//  ALs[r*STR+c], c>=r : A[r][c] (incl diag); c<r : A[c][r] (transposed mirror)
//  SBs[r*STR+c], c>r  : S[r][c] during inside, overwritten with SL = S - log G
//                       as the cell finalizes in the outside pass; diag = 0
//  SBs[c*STR+r], r<c  : softplus(s[r][c]) (preloaded; no global reads in loops)
//  BK[128]            : pipeline carry (bulk partial sums), indexed by cell row
// Pipeline (per phase, ONE barrier): finalize width w = BK[i] + 2 fresh terms
// (from last phase) + log;  bulk for width w+1 from >=1-phase-old data with
// variable group size g (all waves active -> DS latency hidden).
extern "C" __global__ __launch_bounds__(NT, 1) void cky_kernel(
    const float* __restrict__ scores,
    const int* __restrict__ seq_lens,
    float* __restrict__ Z_out,
    float* __restrict__ marg_out)
{
    extern __shared__ float smem[];
    float* ALs = smem;
    float* SBs = smem + LL * STR;
    float* BK  = smem + 2 * LL * STR;

    const int b   = blockIdx.x;
    const int tid = threadIdx.x;
    const float* s = scores + (size_t)b * LL * LL;
    float* marg = marg_out + (size_t)b * LL * LL;
    const int len = seq_lens[b];

    // ---- init: preload softplus; diag A; BK = 0 ----
    for (int idx = tid; idx < LL * LL; idx += NT) {
        const int r = idx >> 7, c = idx & 127;
        const float sp = softplus_f(s[idx]);
        if (c > r)        SBs[c * STR + r] = sp;
        else if (c == r) { ALs[r * STR + r] = sp; SBs[r * STR + r] = 0.f; }
    }
    if (tid < LL) BK[tid] = 0.f;
    lds_barrier();

    // ---- inside w = 1 (exact, single term) ----
    if (tid < len - 1) {
        const int i = tid, j = i + 1;
        const float S = ALs[i * STR + i] + ALs[j * STR + j];
        const float A = S + SBs[j * STR + i];
        ALs[i * STR + j] = A;  ALs[j * STR + i] = A;  SBs[i * STR + j] = S;
    }
    lds_barrier();

    // ---- inside w = 2 .. len-1: finalize w (carry in BK), bulk for w+1 ----
    for (int w = 2; w < len; ++w) {
        const int cells = len - w;
        const int cl = (cells > 1) ? (32 - __clz(cells - 1)) : 0;
        int gsh = 10 - cl; if (gsh > 6) gsh = 6;
        const int g = 1 << gsh, gid = tid >> gsh, v = tid & (g - 1);
        if (gid < cells) {                       // finalize cell (i, i+w)
            const int i = gid, j = i + w;
            const float M    = ALs[i * STR + (j - 2)];   // bulk shift (old)
            const float Ai   = ALs[i * STR + i];
            const float ajm1 = ALs[i * STR + (j - 1)];   // fresh (w-1)
            const float aip1 = ALs[j * STR + (i + 1)];   // fresh (w-1, mirror)
            const float ajj  = ALs[j * STR + j];
            const float spv  = SBs[j * STR + i];
            const float acc  = BK[i]
                             + __expf(Ai   + aip1 - M)   // k = i
                             + __expf(ajm1 + ajj  - M);  // k = j-1  (>= 1)
            if (v == 0) {
                const float S = M + __logf(acc);
                ALs[i * STR + j] = S + spv;
                ALs[j * STR + i] = S + spv;
                SBs[i * STR + j] = S;
            }
        }
        // bulk for width w+1, cell (i, i+w+1): k in [i+1, i+w-1], M2 = A[i][i+w-1]
        float nb = 0.f;
        const int cb = cells - 1;
        if (gid < cb) {
            const int i = gid, j2 = i + w + 1;
            const float M2 = ALs[i * STR + (j2 - 2)];
            const float* Arow = ALs + i * STR;
            const float* Amir = ALs + j2 * STR;
            for (int k = i + 1 + v; k <= j2 - 2; k += g)   // <= ~4 trips
                nb += __expf(Arow[k] + Amir[k + 1] - M2);
        }
        for (int off = g >> 1; off; off >>= 1) nb += __shfl_xor(nb, off);
        if (gid < cb && v == 0) BK[gid] = nb;    // same-wave after the BK read
        lds_barrier();
    }

    if (tid == 0) Z_out[b] = ALs[len - 1];       // A[0][len-1]
    if (tid < LL) BK[tid] = 0.f;                 // GB carry for outside
    lds_barrier();

    // ---- outside w = len-2 .. 0 (gather): finalize w, bulk for w-1 ----
    // Root (0,len-1): G=1 -> SL = S, already in SBs. Terms are <= 1 (no shift).
    for (int w = len - 2; w >= 0; --w) {
        const int cb2 = len - w + 1;             // width-(w-1) cell count (mapping)
        const int cl = (cb2 > 1) ? (32 - __clz(cb2 - 1)) : 0;
        int gsh = 10 - cl; if (gsh > 6) gsh = 6;
        const int g = 1 << gsh, gid = tid >> gsh, v = tid & (g - 1);
        if (gid < len - w) {                     // finalize cell (i, i+w)
            const int i = gid, c = i + w;
            const float Aown = ALs[i * STR + c];
            const float Sown = SBs[i * STR + c];           // still S (diag 0)
            float acc = BK[i];
            if (c + 1 < len)                               // parent (i, c+1), fresh SL
                acc += __expf(Aown + ALs[(c + 1) * STR + (c + 1)]
                                   - SBs[i * STR + (c + 1)]);
            if (i >= 1)                                    // parent (i-1, c), fresh SL
                acc += __expf(ALs[(i - 1) * STR + (i - 1)] + Aown
                                   - SBs[(i - 1) * STR + c]);
            if (v == 0)
                SBs[i * STR + c] = Sown - __logf(acc);     // acc=0 -> +inf (exact 0s)
        }
        // bulk for width w-1, cell (i2, i2+w-1): parents width >= w+1 (old SLs)
        float nb = 0.f;
        if (w >= 1 && gid < cb2) {
            const int i2 = gid, c2 = i2 + w - 1;
            const float Ao2 = ALs[i2 * STR + c2];
            const float* ArowC = ALs + (c2 + 1) * STR;     // A[c2+1][J]
            const float* SLrow = SBs + i2 * STR;           // SL[i2][J]
            for (int J = c2 + 2 + v; J < len; J += g)      // left-parents (i2, J)
                nb += __expf(Ao2 + ArowC[J] - SLrow[J]);
            const float* Amir = ALs + (i2 - 1) * STR;      // A[I][i2-1] mirror row
            for (int I = v; I <= i2 - 2; I += g)           // right-parents (I, c2)
                nb += __expf(Amir[I] + Ao2 - SBs[I * STR + c2]);
        }
        for (int off = g >> 1; off; off >>= 1) nb += __shfl_xor(nb, off);
        if (w >= 1 && gid < cb2 && v == 0) BK[gid] = nb;
        lds_barrier();
    }

    // ---- epilogue: marg = G * sigmoid(s), coalesced ----
    for (int idx = tid; idx < LL * LL; idx += NT) {
        const int r = idx >> 7, c = idx & 127;
        float m = 0.f;
        if (c >= r && c < len) {
            const float sp = softplus_f(s[idx]);
            const float G  = __expf(ALs[r * STR + c] - sp - SBs[r * STR + c]);
            m = G * (1.f - __expf(-sp));
        }
        marg[idx] = m;
    }
}

extern "C" void kernel_launch(void* const* d_in, const int* in_sizes, int n_in,
                              void* d_out, int out_size, void* d_ws, size_t ws_size,
                              hipStream_t stream) {
    const float* scores  = (const float*)d_in[0];
    const int* seq_lens  = (const int*)d_in[1];
    const int B = in_sizes[1];              // 32
    float* out = (float*)d_out;
    float* Z_out = out;                     // B floats
    float* marg  = out + B;                 // B*L*L floats

    const size_t lds_bytes = (size_t)(2 * LL * STR + LL) * sizeof(float);  // 134656 B
    hipFuncSetAttribute((const void*)cky_kernel,
                        hipFuncAttributeMaxDynamicSharedMemorySize,
                        (int)lds_bytes);
    cky_kernel<<<B, NT, lds_bytes, stream>>>(scores, seq_lens, Z_out, marg);
}